// Round 1
// baseline (47602.991 us; speedup 1.0000x reference)
//
#include <hip/hip_runtime.h>

// ---------------------------------------------------------------------------
// LightGCN-style propagation, 4 independent bipartite graphs.
// Per graph: acc=emb; cur=emb; 3x { t = A@cur (scatter rows); cur = A^T@t
// (scatter cols); acc += cur }; out = acc/4.
// Baseline: edge-parallel scatter with HW fp32 atomics (global_atomic_add_f32
// via unsafeAtomicAdd). 32 lanes/edge, float4 per lane (128 floats/row).
// ---------------------------------------------------------------------------

#define D 128           // embedding dim
#define EPB 8           // edges per 256-thread block (32 lanes/edge)

__global__ __launch_bounds__(256) void spmm_scatter_kernel(
    const float* __restrict__ x,        // [n_src, 128] gather source
    float*       __restrict__ y,        // [n_dst, 128] scatter dest (zeroed)
    const float* __restrict__ vals,     // [nnz]
    const int*   __restrict__ src_idx,  // [nnz] index into x
    const int*   __restrict__ dst_idx,  // [nnz] index into y
    int nnz)
{
    int e = blockIdx.x * EPB + (threadIdx.x >> 5);
    if (e >= nnz) return;
    int lane = threadIdx.x & 31;

    float v = vals[e];
    long  s = (long)src_idx[e] << 7;   // *128 floats
    long  d = (long)dst_idx[e] << 7;

    float4 g = *((const float4*)(x + s) + lane);
    float* yd = y + d + lane * 4;
    unsafeAtomicAdd(yd + 0, v * g.x);
    unsafeAtomicAdd(yd + 1, v * g.y);
    unsafeAtomicAdd(yd + 2, v * g.z);
    unsafeAtomicAdd(yd + 3, v * g.w);
}

// out = (out + cur) * scale   over n4 float4 elements
__global__ __launch_bounds__(256) void add_scale_kernel(
    float* __restrict__ out, const float* __restrict__ cur, float scale, int n4)
{
    int i = blockIdx.x * blockDim.x + threadIdx.x;
    if (i >= n4) return;
    float4 o = ((const float4*)out)[i];
    float4 c = ((const float4*)cur)[i];
    o.x = (o.x + c.x) * scale;
    o.y = (o.y + c.y) * scale;
    o.z = (o.z + c.z) * scale;
    o.w = (o.w + c.w) * scale;
    ((float4*)out)[i] = o;
}

extern "C" void kernel_launch(void* const* d_in, const int* in_sizes, int n_in,
                              void* d_out, int out_size, void* d_ws, size_t ws_size,
                              hipStream_t stream)
{
    static const int Ns[4] = {100000, 40000, 20000, 10000};
    static const int Ps[4] = { 40000, 100000, 100000, 40000};

    const float* emb[4];
    const float* vals[4];
    const int*   rows[4];
    const int*   cols[4];
    int nnz[4];
    for (int g = 0; g < 4; ++g) {
        emb[g]  = (const float*)d_in[g];
        vals[g] = (const float*)d_in[4 + g];
        rows[g] = (const int*)d_in[8 + 2 * g];
        cols[g] = (const int*)d_in[8 + 2 * g + 1];
        nnz[g]  = in_sizes[4 + g];
    }

    size_t out_off = 0;
    for (int g = 0; g < 4; ++g) {
        const int N = Ns[g], P = Ps[g], M = nnz[g];
        const size_t nbytesN = (size_t)N * D * sizeof(float);
        const size_t nbytesP = (size_t)P * D * sizeof(float);

        float* cur = (float*)d_ws;                       // [N,128]
        float* t   = (float*)d_ws + (size_t)N * D;       // [P,128]
        float* outg = (float*)d_out + out_off;

        // cur = emb ; acc(out) = emb
        hipMemcpyAsync(cur,  emb[g], nbytesN, hipMemcpyDeviceToDevice, stream);
        hipMemcpyAsync(outg, emb[g], nbytesN, hipMemcpyDeviceToDevice, stream);

        const int spmm_grid = (M + EPB - 1) / EPB;
        const int n4 = N * D / 4;
        const int add_grid = (n4 + 255) / 256;

        for (int layer = 0; layer < 3; ++layer) {
            // t = A @ cur : t[rows[e]] += vals[e] * cur[cols[e]]
            hipMemsetAsync(t, 0, nbytesP, stream);
            spmm_scatter_kernel<<<spmm_grid, 256, 0, stream>>>(
                cur, t, vals[g], cols[g], rows[g], M);
            // cur = A^T @ t : cur[cols[e]] += vals[e] * t[rows[e]]
            hipMemsetAsync(cur, 0, nbytesN, stream);
            spmm_scatter_kernel<<<spmm_grid, 256, 0, stream>>>(
                t, cur, vals[g], rows[g], cols[g], M);
            // acc += cur  (final layer: scale by 1/4)
            float scale = (layer == 2) ? 0.25f : 1.0f;
            add_scale_kernel<<<add_grid, 256, 0, stream>>>(outg, cur, scale, n4);
        }
        out_off += (size_t)N * D;
    }
}

// Round 2
// 4358.373 us; speedup vs baseline: 10.9222x; 10.9222x over previous
//
#include <hip/hip_runtime.h>

// ---------------------------------------------------------------------------
// LightGCN-style propagation, 4 independent bipartite graphs.
// R2: replace atomic-scatter SpMM (3.2 GB HBM write-through per dispatch) with
// on-device CSR build (histogram + scan + scatter, once per launch per graph)
// followed by pure-gather SpMM: one wave per destination row, float2/lane
// register accumulator, single coalesced 512 B row write.
// ---------------------------------------------------------------------------

#define D 128

// --- CSR build step 1: degree histogram for both directions in one pass ---
__global__ __launch_bounds__(256) void count_kernel(
    const int* __restrict__ rows, const int* __restrict__ cols,
    int* __restrict__ degP, int* __restrict__ degN, int nnz)
{
    int e = blockIdx.x * 256 + threadIdx.x;
    if (e >= nnz) return;
    atomicAdd(&degP[rows[e]], 1);
    atomicAdd(&degN[cols[e]], 1);
}

// --- CSR build step 2: exclusive scan, single workgroup, 4 elems/thread ---
// In-place safe: deg may alias cursor (reads of a chunk precede its writes).
__global__ __launch_bounds__(1024) void exscan_kernel(
    const int* __restrict__ deg, int* __restrict__ off,
    int* __restrict__ cursor, int n)
{
    __shared__ int wsum[16];
    __shared__ int s_carry;
    int tid = threadIdx.x;
    int lane = tid & 63, wid = tid >> 6;
    if (tid == 0) s_carry = 0;
    __syncthreads();
    for (int base = 0; base < n; base += 4096) {
        int i0 = base + tid * 4;
        int v0 = (i0 + 0 < n) ? deg[i0 + 0] : 0;
        int v1 = (i0 + 1 < n) ? deg[i0 + 1] : 0;
        int v2 = (i0 + 2 < n) ? deg[i0 + 2] : 0;
        int v3 = (i0 + 3 < n) ? deg[i0 + 3] : 0;
        int tsum = v0 + v1 + v2 + v3;
        // inclusive wave scan of per-thread sums
        int x = tsum;
        #pragma unroll
        for (int s = 1; s < 64; s <<= 1) {
            int y = __shfl_up(x, s, 64);
            if (lane >= s) x += y;
        }
        if (lane == 63) wsum[wid] = x;
        __syncthreads();
        if (tid == 0) {  // serial exclusive scan of 16 wave totals
            int run = 0;
            #pragma unroll
            for (int w = 0; w < 16; ++w) { int t = wsum[w]; wsum[w] = run; run += t; }
        }
        __syncthreads();
        int carry = s_carry;
        int excl = carry + wsum[wid] + (x - tsum);
        if (i0 + 0 < n) { off[i0 + 0] = excl; cursor[i0 + 0] = excl; }
        excl += v0;
        if (i0 + 1 < n) { off[i0 + 1] = excl; cursor[i0 + 1] = excl; }
        excl += v1;
        if (i0 + 2 < n) { off[i0 + 2] = excl; cursor[i0 + 2] = excl; }
        excl += v2;
        if (i0 + 3 < n) { off[i0 + 3] = excl; cursor[i0 + 3] = excl; }
        excl += v3;
        __syncthreads();                  // all reads of wsum/s_carry done
        if (tid == 1023) s_carry = excl;  // = carry + chunk total
    }
    __syncthreads();
    if (tid == 0) off[n] = s_carry;
}

// --- CSR build step 3: scatter {src, val} pairs for both directions ---
__global__ __launch_bounds__(256) void scatter_kernel(
    const int* __restrict__ rows, const int* __restrict__ cols,
    const float* __restrict__ vals,
    int* __restrict__ curP, int* __restrict__ curN,
    int2* __restrict__ pairsP, int2* __restrict__ pairsN, int nnz)
{
    int e = blockIdx.x * 256 + threadIdx.x;
    if (e >= nnz) return;
    int r = rows[e], c = cols[e];
    int vbits = __float_as_int(vals[e]);
    int sp = atomicAdd(&curP[r], 1);
    pairsP[sp] = make_int2(c, vbits);   // row-dir CSR: dst=r, src=c
    int sn = atomicAdd(&curN[c], 1);
    pairsN[sn] = make_int2(r, vbits);   // col-dir CSR: dst=c, src=r
}

// --- gather SpMM: y[row] = sum_e val_e * x[src_e]; one wave per row ---
__global__ __launch_bounds__(256) void spmm_gather_kernel(
    const float* __restrict__ x, float* __restrict__ y,
    const int* __restrict__ off, const int2* __restrict__ pairs, int n_dst)
{
    int row = blockIdx.x * 4 + (threadIdx.x >> 6);
    if (row >= n_dst) return;
    int lane = threadIdx.x & 63;
    int s = off[row], e = off[row + 1];
    float2 acc = make_float2(0.f, 0.f);
    for (int j = s; j < e; ++j) {
        int2 p = pairs[j];
        float v = __int_as_float(p.y);
        float2 g = ((const float2*)(x + ((long)p.x << 7)))[lane];
        acc.x += v * g.x;
        acc.y += v * g.y;
    }
    ((float2*)(y + ((long)row << 7)))[lane] = acc;
}

// --- gather SpMM fused with accumulator update: also out=(out+acc)*scale ---
__global__ __launch_bounds__(256) void spmm_gather_acc_kernel(
    const float* __restrict__ x, float* __restrict__ y,
    float* __restrict__ out,
    const int* __restrict__ off, const int2* __restrict__ pairs,
    int n_dst, float scale)
{
    int row = blockIdx.x * 4 + (threadIdx.x >> 6);
    if (row >= n_dst) return;
    int lane = threadIdx.x & 63;
    int s = off[row], e = off[row + 1];
    float2 acc = make_float2(0.f, 0.f);
    for (int j = s; j < e; ++j) {
        int2 p = pairs[j];
        float v = __int_as_float(p.y);
        float2 g = ((const float2*)(x + ((long)p.x << 7)))[lane];
        acc.x += v * g.x;
        acc.y += v * g.y;
    }
    long rbase = (long)row << 7;
    ((float2*)(y + rbase))[lane] = acc;
    float2 o = ((const float2*)(out + rbase))[lane];
    o.x = (o.x + acc.x) * scale;
    o.y = (o.y + acc.y) * scale;
    ((float2*)(out + rbase))[lane] = o;
}

extern "C" void kernel_launch(void* const* d_in, const int* in_sizes, int n_in,
                              void* d_out, int out_size, void* d_ws, size_t ws_size,
                              hipStream_t stream)
{
    static const int Ns[4] = {100000, 40000, 20000, 10000};
    static const int Ps[4] = { 40000, 100000, 100000, 40000};

    size_t out_off = 0;
    for (int g = 0; g < 4; ++g) {
        const float* emb  = (const float*)d_in[g];
        const float* vals = (const float*)d_in[4 + g];
        const int*   rows = (const int*)d_in[8 + 2 * g];
        const int*   cols = (const int*)d_in[8 + 2 * g + 1];
        const int    M    = in_sizes[4 + g];
        const int    N    = Ns[g], P = Ps[g];

        // -- workspace carve (reused across graphs), 256 B aligned --
        char* wp = (char*)d_ws;
        auto alloc = [&](size_t bytes) -> void* {
            void* p = (void*)wp; wp += (bytes + 255) & ~(size_t)255; return p;
        };
        float* curb   = (float*)alloc((size_t)N * D * sizeof(float));
        float* t      = (float*)alloc((size_t)P * D * sizeof(float));
        int*   offP   = (int*)  alloc((size_t)(P + 1) * sizeof(int));
        int*   curP   = (int*)  alloc((size_t)P * sizeof(int));
        int*   offN   = (int*)  alloc((size_t)(N + 1) * sizeof(int));
        int*   curN   = (int*)  alloc((size_t)N * sizeof(int));
        int2*  pairsP = (int2*) alloc((size_t)M * sizeof(int2));
        int2*  pairsN = (int2*) alloc((size_t)M * sizeof(int2));

        float* outg = (float*)d_out + out_off;
        const size_t nbytesN = (size_t)N * D * sizeof(float);

        // -- CSR build (both directions) --
        hipMemsetAsync(curP, 0, (size_t)P * sizeof(int), stream);
        hipMemsetAsync(curN, 0, (size_t)N * sizeof(int), stream);
        int egrid = (M + 255) / 256;
        count_kernel<<<egrid, 256, 0, stream>>>(rows, cols, curP, curN, M);
        exscan_kernel<<<1, 1024, 0, stream>>>(curP, offP, curP, P);
        exscan_kernel<<<1, 1024, 0, stream>>>(curN, offN, curN, N);
        scatter_kernel<<<egrid, 256, 0, stream>>>(rows, cols, vals,
                                                  curP, curN, pairsP, pairsN, M);

        // -- acc init: out = emb --
        hipMemcpyAsync(outg, emb, nbytesN, hipMemcpyDeviceToDevice, stream);

        const int gridP = (P + 3) / 4;
        const int gridN = (N + 3) / 4;
        for (int layer = 0; layer < 3; ++layer) {
            const float* src = (layer == 0) ? emb : curb;
            // t = A @ src  (dst = partner rows)
            spmm_gather_kernel<<<gridP, 256, 0, stream>>>(src, t, offP, pairsP, P);
            // cur = A^T @ t, fused: out = (out + cur) * scale
            float scale = (layer == 2) ? 0.25f : 1.0f;
            spmm_gather_acc_kernel<<<gridN, 256, 0, stream>>>(
                t, curb, outg, offN, pairsN, N, scale);
        }
        out_off += (size_t)N * D;
    }
}

// Round 3
// 3130.974 us; speedup vs baseline: 15.2039x; 1.3920x over previous
//
#include <hip/hip_runtime.h>

// ---------------------------------------------------------------------------
// LightGCN-style propagation, 4 independent bipartite graphs.
// R3: (a) CSR build for ALL graphs up front -> the 8 exclusive scans run as
// 8 workgroups in one launch (was 8 serial single-WG launches);
// (b) gather SpMM: 64-lane wave per row, 2 edges/iter (half-wave each,
// no divergence), float4/lane, unroll-2 -> 4 row-loads in flight;
// (c) accumulator fused into N-side epilogues (no memcpy, no extra add pass).
// Scatter write amplification (1 line per random 8B pair write) accepted.
// ---------------------------------------------------------------------------

#define D 128

struct GDesc {
    const int* rows; const int* cols; const float* vals;
    int* curP; int* curN;
    int2* pairsP; int2* pairsN;
    int nnz; int blkBase;
};
struct GDesc4 { GDesc d[4]; };

struct SDesc { int* degcur; int* off; int n; };   // degcur: in-place deg->cursor
struct SDesc8 { SDesc s[8]; };

// --- degree histogram, all graphs, one launch ---
__global__ __launch_bounds__(256) void count_all_kernel(GDesc4 G)
{
    int b = blockIdx.x;
    int g = (b >= G.d[1].blkBase) + (b >= G.d[2].blkBase) + (b >= G.d[3].blkBase);
    const GDesc E = G.d[g];
    int e = (b - E.blkBase) * 256 + threadIdx.x;
    if (e >= E.nnz) return;
    atomicAdd(&E.curP[E.rows[e]], 1);
    atomicAdd(&E.curN[E.cols[e]], 1);
}

// --- 8 exclusive scans (P/N x 4 graphs), one workgroup each ---
__global__ __launch_bounds__(1024) void exscan_all_kernel(SDesc8 S)
{
    SDesc sd = S.s[blockIdx.x];
    const int* deg = sd.degcur;
    int* off = sd.off;
    int* cursor = sd.degcur;
    int n = sd.n;

    __shared__ int wsum[16];
    __shared__ int s_carry;
    int tid = threadIdx.x;
    int lane = tid & 63, wid = tid >> 6;
    if (tid == 0) s_carry = 0;
    __syncthreads();
    for (int base = 0; base < n; base += 4096) {
        int i0 = base + tid * 4;
        int v0 = (i0 + 0 < n) ? deg[i0 + 0] : 0;
        int v1 = (i0 + 1 < n) ? deg[i0 + 1] : 0;
        int v2 = (i0 + 2 < n) ? deg[i0 + 2] : 0;
        int v3 = (i0 + 3 < n) ? deg[i0 + 3] : 0;
        int tsum = v0 + v1 + v2 + v3;
        int x = tsum;
        #pragma unroll
        for (int s = 1; s < 64; s <<= 1) {
            int y = __shfl_up(x, s, 64);
            if (lane >= s) x += y;
        }
        if (lane == 63) wsum[wid] = x;
        __syncthreads();
        if (tid == 0) {
            int run = 0;
            #pragma unroll
            for (int w = 0; w < 16; ++w) { int t = wsum[w]; wsum[w] = run; run += t; }
        }
        __syncthreads();
        int carry = s_carry;
        int excl = carry + wsum[wid] + (x - tsum);
        if (i0 + 0 < n) { off[i0 + 0] = excl; cursor[i0 + 0] = excl; }
        excl += v0;
        if (i0 + 1 < n) { off[i0 + 1] = excl; cursor[i0 + 1] = excl; }
        excl += v1;
        if (i0 + 2 < n) { off[i0 + 2] = excl; cursor[i0 + 2] = excl; }
        excl += v2;
        if (i0 + 3 < n) { off[i0 + 3] = excl; cursor[i0 + 3] = excl; }
        excl += v3;
        __syncthreads();
        if (tid == 1023) s_carry = excl;
    }
    __syncthreads();
    if (tid == 0) off[n] = s_carry;
}

// --- pair scatter, all graphs, one launch ---
__global__ __launch_bounds__(256) void scatter_all_kernel(GDesc4 G)
{
    int b = blockIdx.x;
    int g = (b >= G.d[1].blkBase) + (b >= G.d[2].blkBase) + (b >= G.d[3].blkBase);
    const GDesc E = G.d[g];
    int e = (b - E.blkBase) * 256 + threadIdx.x;
    if (e >= E.nnz) return;
    int r = E.rows[e], c = E.cols[e];
    int vbits = __float_as_int(E.vals[e]);
    int sp = atomicAdd(&E.curP[r], 1);
    E.pairsP[sp] = make_int2(c, vbits);
    int sn = atomicAdd(&E.curN[c], 1);
    E.pairsN[sn] = make_int2(r, vbits);
}

// --- gather SpMM: one 64-lane wave per row, 2 edges/iter, float4/lane ---
// MODE 0: y = acc                         (P-side -> t)
// MODE 1: y = acc; out = aux(emb) + acc   (N-side layer 1)
// MODE 2: y = acc; out += acc             (N-side layer 2)
// MODE 3: out = (out + acc) * 0.25        (N-side layer 3, no y write)
template<int MODE>
__global__ __launch_bounds__(256) void spmm_kernel(
    const float* __restrict__ x, float* __restrict__ y,
    float* __restrict__ out, const float* __restrict__ aux,
    const int* __restrict__ off, const int2* __restrict__ pairs, int n_dst)
{
    int row = blockIdx.x * 4 + (threadIdx.x >> 6);
    if (row >= n_dst) return;
    int lane = threadIdx.x & 63;
    int half = lane >> 5;
    int l32  = lane & 31;

    int s = off[row], e = off[row + 1];
    float4 acc = make_float4(0.f, 0.f, 0.f, 0.f);
    int j = s + half;
    for (; j + 2 < e; j += 4) {
        int2 p0 = pairs[j];
        int2 p1 = pairs[j + 2];
        float v0 = __int_as_float(p0.y);
        float v1 = __int_as_float(p1.y);
        float4 g0 = ((const float4*)(x + ((long)p0.x << 7)))[l32];
        float4 g1 = ((const float4*)(x + ((long)p1.x << 7)))[l32];
        acc.x += v0 * g0.x; acc.y += v0 * g0.y;
        acc.z += v0 * g0.z; acc.w += v0 * g0.w;
        acc.x += v1 * g1.x; acc.y += v1 * g1.y;
        acc.z += v1 * g1.z; acc.w += v1 * g1.w;
    }
    if (j < e) {
        int2 p = pairs[j];
        float v = __int_as_float(p.y);
        float4 g = ((const float4*)(x + ((long)p.x << 7)))[l32];
        acc.x += v * g.x; acc.y += v * g.y;
        acc.z += v * g.z; acc.w += v * g.w;
    }
    // combine the two half-wave partial sums
    acc.x += __shfl_xor(acc.x, 32);
    acc.y += __shfl_xor(acc.y, 32);
    acc.z += __shfl_xor(acc.z, 32);
    acc.w += __shfl_xor(acc.w, 32);

    if (half == 0) {
        long rbase = (long)row << 7;
        if (MODE == 0) {
            ((float4*)(y + rbase))[l32] = acc;
        } else if (MODE == 1) {
            ((float4*)(y + rbase))[l32] = acc;
            float4 eb = ((const float4*)(aux + rbase))[l32];
            eb.x += acc.x; eb.y += acc.y; eb.z += acc.z; eb.w += acc.w;
            ((float4*)(out + rbase))[l32] = eb;
        } else if (MODE == 2) {
            ((float4*)(y + rbase))[l32] = acc;
            float4 o = ((const float4*)(out + rbase))[l32];
            o.x += acc.x; o.y += acc.y; o.z += acc.z; o.w += acc.w;
            ((float4*)(out + rbase))[l32] = o;
        } else {
            float4 o = ((const float4*)(out + rbase))[l32];
            o.x = (o.x + acc.x) * 0.25f;
            o.y = (o.y + acc.y) * 0.25f;
            o.z = (o.z + acc.z) * 0.25f;
            o.w = (o.w + acc.w) * 0.25f;
            ((float4*)(out + rbase))[l32] = o;
        }
    }
}

extern "C" void kernel_launch(void* const* d_in, const int* in_sizes, int n_in,
                              void* d_out, int out_size, void* d_ws, size_t ws_size,
                              hipStream_t stream)
{
    static const int Ns[4] = {100000, 40000, 20000, 10000};
    static const int Ps[4] = { 40000, 100000, 100000, 40000};
    const int maxN = 100000, maxP = 100000;

    int nnz[4];
    for (int g = 0; g < 4; ++g) nnz[g] = in_sizes[4 + g];

    // ---- workspace carve ----
    char* wp = (char*)d_ws;
    auto alloc = [&](size_t bytes) -> void* {
        void* p = (void*)wp; wp += (bytes + 255) & ~(size_t)255; return p;
    };
    float* cur = (float*)alloc((size_t)maxN * D * sizeof(float));  // shared
    float* t   = (float*)alloc((size_t)maxP * D * sizeof(float));  // shared
    // cursors contiguous (single memset), then offsets, then pairs
    int* curP[4]; int* curN[4];
    char* cursor_base = wp;
    for (int g = 0; g < 4; ++g) {
        curP[g] = (int*)alloc((size_t)Ps[g] * sizeof(int));
        curN[g] = (int*)alloc((size_t)Ns[g] * sizeof(int));
    }
    size_t cursor_bytes = (size_t)(wp - cursor_base);
    int* offP[4]; int* offN[4]; int2* pairsP[4]; int2* pairsN[4];
    for (int g = 0; g < 4; ++g) {
        offP[g] = (int*)alloc((size_t)(Ps[g] + 1) * sizeof(int));
        offN[g] = (int*)alloc((size_t)(Ns[g] + 1) * sizeof(int));
    }
    for (int g = 0; g < 4; ++g) {
        pairsP[g] = (int2*)alloc((size_t)nnz[g] * sizeof(int2));
        pairsN[g] = (int2*)alloc((size_t)nnz[g] * sizeof(int2));
    }

    // ---- descriptors ----
    GDesc4 G;
    int blkBase = 0;
    for (int g = 0; g < 4; ++g) {
        G.d[g].rows = (const int*)d_in[8 + 2 * g];
        G.d[g].cols = (const int*)d_in[8 + 2 * g + 1];
        G.d[g].vals = (const float*)d_in[4 + g];
        G.d[g].curP = curP[g];  G.d[g].curN = curN[g];
        G.d[g].pairsP = pairsP[g];  G.d[g].pairsN = pairsN[g];
        G.d[g].nnz = nnz[g];
        G.d[g].blkBase = blkBase;
        blkBase += (nnz[g] + 255) / 256;
    }
    SDesc8 S;
    for (int g = 0; g < 4; ++g) {
        S.s[2 * g + 0] = { curP[g], offP[g], Ps[g] };
        S.s[2 * g + 1] = { curN[g], offN[g], Ns[g] };
    }

    // ---- CSR build (all graphs) ----
    hipMemsetAsync(cursor_base, 0, cursor_bytes, stream);
    count_all_kernel<<<blkBase, 256, 0, stream>>>(G);
    exscan_all_kernel<<<8, 1024, 0, stream>>>(S);
    scatter_all_kernel<<<blkBase, 256, 0, stream>>>(G);

    // ---- propagation, per graph ----
    size_t out_off = 0;
    for (int g = 0; g < 4; ++g) {
        const float* emb = (const float*)d_in[g];
        float* outg = (float*)d_out + out_off;
        const int N = Ns[g], P = Ps[g];
        const int gridP = (P + 3) / 4;
        const int gridN = (N + 3) / 4;

        // layer 1
        spmm_kernel<0><<<gridP, 256, 0, stream>>>(emb, t, nullptr, nullptr,
                                                  offP[g], pairsP[g], P);
        spmm_kernel<1><<<gridN, 256, 0, stream>>>(t, cur, outg, emb,
                                                  offN[g], pairsN[g], N);
        // layer 2
        spmm_kernel<0><<<gridP, 256, 0, stream>>>(cur, t, nullptr, nullptr,
                                                  offP[g], pairsP[g], P);
        spmm_kernel<2><<<gridN, 256, 0, stream>>>(t, cur, outg, nullptr,
                                                  offN[g], pairsN[g], N);
        // layer 3
        spmm_kernel<0><<<gridP, 256, 0, stream>>>(cur, t, nullptr, nullptr,
                                                  offP[g], pairsP[g], P);
        spmm_kernel<3><<<gridN, 256, 0, stream>>>(t, nullptr, outg, nullptr,
                                                  offN[g], pairsN[g], N);

        out_off += (size_t)N * D;
    }
}

// Round 4
// 2085.145 us; speedup vs baseline: 22.8296x; 1.5016x over previous
//
#include <hip/hip_runtime.h>

// ---------------------------------------------------------------------------
// LightGCN-style propagation, 4 independent bipartite graphs.
// R4: (a) dest-bucketed CSR scatter — each (dir,bucket) block-slice rescans
// the edge stream and scatters only edges whose dest falls in a ~2MB pair
// window, so random 8B writes coalesce in L2 before eviction (kills the
// 546MB->70MB write amplification of the single-pass scatter);
// (b) bf16 intermediates (emb_bf/t/cur) with fp32 register accumulation and
// fp32 out — halves the dominant nnz*rowbytes gather traffic;
// (c) SpMM: quarter-wave gather (16 lanes/edge, uint4 = 8 bf16/lane,
// 8 edges in flight per wave iteration).
// ---------------------------------------------------------------------------

#define D 128

// ---- bf16 helpers (RNE pack, bit-shift unpack) ----
__device__ __forceinline__ unsigned f2bf(float f) {
    unsigned u = __float_as_uint(f);
    u += 0x7FFFu + ((u >> 16) & 1u);
    return u >> 16;
}
__device__ __forceinline__ float bflo(unsigned u) { return __uint_as_float(u << 16); }
__device__ __forceinline__ float bfhi(unsigned u) { return __uint_as_float(u & 0xFFFF0000u); }

// ---- fp32 -> bf16 row conversion (8 elems/thread) ----
__global__ __launch_bounds__(256) void cvt_bf16_kernel(
    const float* __restrict__ x, uint4* __restrict__ y, int n8)
{
    int i = blockIdx.x * 256 + threadIdx.x;
    if (i >= n8) return;
    const float4* xp = (const float4*)x + (size_t)i * 2;
    float4 a = xp[0], b = xp[1];
    uint4 o;
    o.x = f2bf(a.x) | (f2bf(a.y) << 16);
    o.y = f2bf(a.z) | (f2bf(a.w) << 16);
    o.z = f2bf(b.x) | (f2bf(b.y) << 16);
    o.w = f2bf(b.z) | (f2bf(b.w) << 16);
    y[i] = o;
}

// ---- CSR build: degree histogram, all graphs, one launch ----
struct CDesc {
    const int* rows; const int* cols;
    int* curP; int* curN;
    int nnz; int blkBase;
};
struct CDesc4 { CDesc d[4]; };

__global__ __launch_bounds__(256) void count_all_kernel(CDesc4 G)
{
    int b = blockIdx.x;
    int g = (b >= G.d[1].blkBase) + (b >= G.d[2].blkBase) + (b >= G.d[3].blkBase);
    const CDesc E = G.d[g];
    int e = (b - E.blkBase) * 256 + threadIdx.x;
    if (e >= E.nnz) return;
    atomicAdd(&E.curP[E.rows[e]], 1);
    atomicAdd(&E.curN[E.cols[e]], 1);
}

// ---- CSR build: 8 exclusive scans, one workgroup each ----
struct SDesc { int* degcur; int* off; int n; };
struct SDesc8 { SDesc s[8]; };

__global__ __launch_bounds__(1024) void exscan_all_kernel(SDesc8 S)
{
    SDesc sd = S.s[blockIdx.x];
    const int* deg = sd.degcur;
    int* off = sd.off;
    int* cursor = sd.degcur;
    int n = sd.n;

    __shared__ int wsum[16];
    __shared__ int s_carry;
    int tid = threadIdx.x;
    int lane = tid & 63, wid = tid >> 6;
    if (tid == 0) s_carry = 0;
    __syncthreads();
    for (int base = 0; base < n; base += 4096) {
        int i0 = base + tid * 4;
        int v0 = (i0 + 0 < n) ? deg[i0 + 0] : 0;
        int v1 = (i0 + 1 < n) ? deg[i0 + 1] : 0;
        int v2 = (i0 + 2 < n) ? deg[i0 + 2] : 0;
        int v3 = (i0 + 3 < n) ? deg[i0 + 3] : 0;
        int tsum = v0 + v1 + v2 + v3;
        int x = tsum;
        #pragma unroll
        for (int s = 1; s < 64; s <<= 1) {
            int y = __shfl_up(x, s, 64);
            if (lane >= s) x += y;
        }
        if (lane == 63) wsum[wid] = x;
        __syncthreads();
        if (tid == 0) {
            int run = 0;
            #pragma unroll
            for (int w = 0; w < 16; ++w) { int t = wsum[w]; wsum[w] = run; run += t; }
        }
        __syncthreads();
        int carry = s_carry;
        int excl = carry + wsum[wid] + (x - tsum);
        if (i0 + 0 < n) { off[i0 + 0] = excl; cursor[i0 + 0] = excl; }
        excl += v0;
        if (i0 + 1 < n) { off[i0 + 1] = excl; cursor[i0 + 1] = excl; }
        excl += v1;
        if (i0 + 2 < n) { off[i0 + 2] = excl; cursor[i0 + 2] = excl; }
        excl += v2;
        if (i0 + 3 < n) { off[i0 + 3] = excl; cursor[i0 + 3] = excl; }
        excl += v3;
        __syncthreads();
        if (tid == 1023) s_carry = excl;
    }
    __syncthreads();
    if (tid == 0) off[n] = s_carry;
}

// ---- CSR build: dest-bucketed pair scatter (per graph launch) ----
// blockIdx.y selects (dir, bucket). Each block scans a 4096-edge chunk and
// scatters only edges whose dest>>shift == bucket. The live write window per
// bucket is <= ~2MB, so L2 coalesces the random 8B pair writes into full
// lines before they reach HBM.
struct ScatArgs {
    const int* rows; const int* cols; const float* vals;
    int* curP; int* curN; int2* pairsP; int2* pairsN;
    int nnz; int BP; int shiftP; int shiftN;
};
__global__ __launch_bounds__(256) void bucket_scatter_kernel(ScatArgs A)
{
    int by = blockIdx.y;
    const int* dst; const int* src; int* cursor; int2* pairs; int bucket, shift;
    if (by < A.BP) {
        dst = A.rows; src = A.cols; cursor = A.curP; pairs = A.pairsP;
        bucket = by; shift = A.shiftP;
    } else {
        dst = A.cols; src = A.rows; cursor = A.curN; pairs = A.pairsN;
        bucket = by - A.BP; shift = A.shiftN;
    }
    int base = blockIdx.x * 4096 + threadIdx.x;
    #pragma unroll 4
    for (int k = 0; k < 16; ++k) {
        int e = base + k * 256;
        if (e >= A.nnz) break;
        int d = dst[e];
        if ((d >> shift) == bucket) {
            int s = src[e];
            float v = A.vals[e];
            int pos = atomicAdd(&cursor[d], 1);
            pairs[pos] = make_int2(s, __float_as_int(v));
        }
    }
}

// ---- gather SpMM: one wave per row, quarter-wave per edge, bf16 rows ----
// MODE 0: y = acc                          (P-side -> t)
// MODE 1: y = acc; out = aux(emb) + acc    (N-side layer 1)
// MODE 2: y = acc; out += acc              (N-side layer 2)
// MODE 3: out = (out + acc) * 0.25         (N-side layer 3)
template<int MODE>
__global__ __launch_bounds__(256) void spmm_kernel(
    const unsigned short* __restrict__ x,   // bf16 [n_src][128]
    unsigned short* __restrict__ y,         // bf16 [n_dst][128]
    float* __restrict__ out,                // fp32 [n_dst][128]
    const float* __restrict__ aux,          // fp32 emb (MODE 1)
    const int* __restrict__ off, const int2* __restrict__ pairs, int n_dst)
{
    int row = blockIdx.x * 4 + (threadIdx.x >> 6);
    if (row >= n_dst) return;
    int lane = threadIdx.x & 63;
    int q   = lane >> 4;     // quarter 0..3 -> edge j+q
    int l16 = lane & 15;     // elems l16*8 .. l16*8+7

    int s = off[row], e = off[row + 1];
    float acc[8] = {0.f,0.f,0.f,0.f,0.f,0.f,0.f,0.f};

    int j = s;
    for (; j + 7 < e; j += 8) {            // 8 edges/iter, all valid
        int2 p0 = pairs[j + q];
        int2 p1 = pairs[j + 4 + q];
        float v0 = __int_as_float(p0.y);
        float v1 = __int_as_float(p1.y);
        uint4 g0 = ((const uint4*)(x + ((long)p0.x << 7)))[l16];
        uint4 g1 = ((const uint4*)(x + ((long)p1.x << 7)))[l16];
        acc[0] += v0 * bflo(g0.x); acc[1] += v0 * bfhi(g0.x);
        acc[2] += v0 * bflo(g0.y); acc[3] += v0 * bfhi(g0.y);
        acc[4] += v0 * bflo(g0.z); acc[5] += v0 * bfhi(g0.z);
        acc[6] += v0 * bflo(g0.w); acc[7] += v0 * bfhi(g0.w);
        acc[0] += v1 * bflo(g1.x); acc[1] += v1 * bfhi(g1.x);
        acc[2] += v1 * bflo(g1.y); acc[3] += v1 * bfhi(g1.y);
        acc[4] += v1 * bflo(g1.z); acc[5] += v1 * bfhi(g1.z);
        acc[6] += v1 * bflo(g1.w); acc[7] += v1 * bfhi(g1.w);
    }
    for (; j < e; j += 4) {                // predicated tail quad
        if (j + q < e) {
            int2 p = pairs[j + q];
            float v = __int_as_float(p.y);
            uint4 g = ((const uint4*)(x + ((long)p.x << 7)))[l16];
            acc[0] += v * bflo(g.x); acc[1] += v * bfhi(g.x);
            acc[2] += v * bflo(g.y); acc[3] += v * bfhi(g.y);
            acc[4] += v * bflo(g.z); acc[5] += v * bfhi(g.z);
            acc[6] += v * bflo(g.w); acc[7] += v * bfhi(g.w);
        }
    }
    #pragma unroll
    for (int k = 0; k < 8; ++k) {          // combine 4 quarter partials
        acc[k] += __shfl_xor(acc[k], 16);
        acc[k] += __shfl_xor(acc[k], 32);
    }
    if (q != 0) return;
    long rb = (long)row << 7;
    if (MODE != 3) {
        uint4 o;
        o.x = f2bf(acc[0]) | (f2bf(acc[1]) << 16);
        o.y = f2bf(acc[2]) | (f2bf(acc[3]) << 16);
        o.z = f2bf(acc[4]) | (f2bf(acc[5]) << 16);
        o.w = f2bf(acc[6]) | (f2bf(acc[7]) << 16);
        ((uint4*)(y + rb))[l16] = o;
    }
    if (MODE == 1) {
        const float4* ap = (const float4*)(aux + rb) + l16 * 2;
        float4* op = (float4*)(out + rb) + l16 * 2;
        float4 a0 = ap[0], a1 = ap[1];
        a0.x += acc[0]; a0.y += acc[1]; a0.z += acc[2]; a0.w += acc[3];
        a1.x += acc[4]; a1.y += acc[5]; a1.z += acc[6]; a1.w += acc[7];
        op[0] = a0; op[1] = a1;
    } else if (MODE == 2) {
        float4* op = (float4*)(out + rb) + l16 * 2;
        float4 a0 = op[0], a1 = op[1];
        a0.x += acc[0]; a0.y += acc[1]; a0.z += acc[2]; a0.w += acc[3];
        a1.x += acc[4]; a1.y += acc[5]; a1.z += acc[6]; a1.w += acc[7];
        op[0] = a0; op[1] = a1;
    } else if (MODE == 3) {
        float4* op = (float4*)(out + rb) + l16 * 2;
        float4 a0 = op[0], a1 = op[1];
        a0.x = (a0.x + acc[0]) * 0.25f; a0.y = (a0.y + acc[1]) * 0.25f;
        a0.z = (a0.z + acc[2]) * 0.25f; a0.w = (a0.w + acc[3]) * 0.25f;
        a1.x = (a1.x + acc[4]) * 0.25f; a1.y = (a1.y + acc[5]) * 0.25f;
        a1.z = (a1.z + acc[6]) * 0.25f; a1.w = (a1.w + acc[7]) * 0.25f;
        op[0] = a0; op[1] = a1;
    }
}

extern "C" void kernel_launch(void* const* d_in, const int* in_sizes, int n_in,
                              void* d_out, int out_size, void* d_ws, size_t ws_size,
                              hipStream_t stream)
{
    static const int Ns[4] = {100000, 40000, 20000, 10000};
    static const int Ps[4] = { 40000, 100000, 100000, 40000};
    const int maxN = 100000, maxP = 100000;

    int nnz[4];
    for (int g = 0; g < 4; ++g) nnz[g] = in_sizes[4 + g];

    // ---- workspace carve ----
    char* wp = (char*)d_ws;
    auto alloc = [&](size_t bytes) -> void* {
        void* p = (void*)wp; wp += (bytes + 255) & ~(size_t)255; return p;
    };
    unsigned short* cur = (unsigned short*)alloc((size_t)maxN * D * 2);  // bf16, also emb_bf
    unsigned short* t   = (unsigned short*)alloc((size_t)maxP * D * 2);  // bf16
    int* curP[4]; int* curN[4];
    char* cursor_base = wp;
    for (int g = 0; g < 4; ++g) {
        curP[g] = (int*)alloc((size_t)Ps[g] * sizeof(int));
        curN[g] = (int*)alloc((size_t)Ns[g] * sizeof(int));
    }
    size_t cursor_bytes = (size_t)(wp - cursor_base);
    int* offP[4]; int* offN[4]; int2* pairsP[4]; int2* pairsN[4];
    for (int g = 0; g < 4; ++g) {
        offP[g] = (int*)alloc((size_t)(Ps[g] + 1) * sizeof(int));
        offN[g] = (int*)alloc((size_t)(Ns[g] + 1) * sizeof(int));
    }
    for (int g = 0; g < 4; ++g) {
        pairsP[g] = (int2*)alloc((size_t)nnz[g] * sizeof(int2));
        pairsN[g] = (int2*)alloc((size_t)nnz[g] * sizeof(int2));
    }

    // ---- CSR build: count + scan ----
    CDesc4 G;
    int blkBase = 0;
    for (int g = 0; g < 4; ++g) {
        G.d[g].rows = (const int*)d_in[8 + 2 * g];
        G.d[g].cols = (const int*)d_in[8 + 2 * g + 1];
        G.d[g].curP = curP[g];  G.d[g].curN = curN[g];
        G.d[g].nnz = nnz[g];
        G.d[g].blkBase = blkBase;
        blkBase += (nnz[g] + 255) / 256;
    }
    SDesc8 S;
    for (int g = 0; g < 4; ++g) {
        S.s[2 * g + 0] = { curP[g], offP[g], Ps[g] };
        S.s[2 * g + 1] = { curN[g], offN[g], Ns[g] };
    }
    hipMemsetAsync(cursor_base, 0, cursor_bytes, stream);
    count_all_kernel<<<blkBase, 256, 0, stream>>>(G);
    exscan_all_kernel<<<8, 1024, 0, stream>>>(S);

    // ---- CSR build: bucketed scatter, one launch per graph ----
    // bucket span: largest pow2 with pair window nnz*8*span/n <= 2MB
    auto calc_shift = [](int n, int m) {
        double span_max = 262144.0 * n / m;
        int shift = 0;
        while ((1 << (shift + 1)) <= (int)span_max && shift < 17) ++shift;
        return shift;
    };
    for (int g = 0; g < 4; ++g) {
        ScatArgs A;
        A.rows = (const int*)d_in[8 + 2 * g];
        A.cols = (const int*)d_in[8 + 2 * g + 1];
        A.vals = (const float*)d_in[4 + g];
        A.curP = curP[g]; A.curN = curN[g];
        A.pairsP = pairsP[g]; A.pairsN = pairsN[g];
        A.nnz = nnz[g];
        A.shiftP = calc_shift(Ps[g], nnz[g]);
        A.shiftN = calc_shift(Ns[g], nnz[g]);
        A.BP = (Ps[g] + (1 << A.shiftP) - 1) >> A.shiftP;
        int BN = (Ns[g] + (1 << A.shiftN) - 1) >> A.shiftN;
        dim3 grid((nnz[g] + 4095) / 4096, A.BP + BN);
        bucket_scatter_kernel<<<grid, 256, 0, stream>>>(A);
    }

    // ---- propagation, per graph ----
    size_t out_off = 0;
    for (int g = 0; g < 4; ++g) {
        const float* emb = (const float*)d_in[g];
        float* outg = (float*)d_out + out_off;
        const int N = Ns[g], P = Ps[g];
        const int gridP = (P + 3) / 4;
        const int gridN = (N + 3) / 4;

        // emb -> bf16 into cur (consumed by layer-1 P-side before overwrite)
        int n8 = N * D / 8;
        cvt_bf16_kernel<<<(n8 + 255) / 256, 256, 0, stream>>>(emb, (uint4*)cur, n8);

        // layer 1
        spmm_kernel<0><<<gridP, 256, 0, stream>>>(cur, t, nullptr, nullptr,
                                                  offP[g], pairsP[g], P);
        spmm_kernel<1><<<gridN, 256, 0, stream>>>(t, cur, outg, emb,
                                                  offN[g], pairsN[g], N);
        // layer 2
        spmm_kernel<0><<<gridP, 256, 0, stream>>>(cur, t, nullptr, nullptr,
                                                  offP[g], pairsP[g], P);
        spmm_kernel<2><<<gridN, 256, 0, stream>>>(t, cur, outg, nullptr,
                                                  offN[g], pairsN[g], N);
        // layer 3
        spmm_kernel<0><<<gridP, 256, 0, stream>>>(cur, t, nullptr, nullptr,
                                                  offP[g], pairsP[g], P);
        spmm_kernel<3><<<gridN, 256, 0, stream>>>(t, nullptr, outg, nullptr,
                                                  offN[g], pairsN[g], N);

        out_off += (size_t)N * D;
    }
}